// Round 9
// baseline (128.951 us; speedup 1.0000x reference)
//
#include <hip/hip_runtime.h>
#include <hip/hip_bf16.h>

#define S_ 2048
#define D_ 512
#define HD_ 64
#define HH_ 8
#define M_ 8192

typedef __attribute__((ext_vector_type(8))) short short8;
typedef __attribute__((ext_vector_type(4))) short short4v;
typedef __attribute__((ext_vector_type(4))) float f32x4;

__device__ __forceinline__ unsigned short f2bf(float f) {
  unsigned u = __builtin_bit_cast(unsigned, f);
  u += 0x7fffu + ((u >> 16) & 1u);
  return (unsigned short)(u >> 16);
}

__device__ __forceinline__ f32x4 mfma16(short8 a, short8 b, f32x4 c) {
  return __builtin_amdgcn_mfma_f32_16x16x32_bf16(a, b, c, 0, 0, 0);
}

#define GLOAD_LDS16(gp, lp)                                                        \
  __builtin_amdgcn_global_load_lds(                                                \
      (const __attribute__((address_space(1))) void*)(gp),                         \
      (__attribute__((address_space(3))) void*)(lp), 16, 0, 0)

// ---------------- converts ----------------

__global__ __launch_bounds__(256) void k_cvt_bf16x8(const float* __restrict__ x,
                                                    short* __restrict__ o) {
  int idx = blockIdx.x * 256 + threadIdx.x;
  const float4* p = (const float4*)x;
  float4 a = p[idx * 2];
  float4 b = p[idx * 2 + 1];
  short8 v;
  v[0] = (short)f2bf(a.x); v[1] = (short)f2bf(a.y);
  v[2] = (short)f2bf(a.z); v[3] = (short)f2bf(a.w);
  v[4] = (short)f2bf(b.x); v[5] = (short)f2bf(b.y);
  v[6] = (short)f2bf(b.z); v[7] = (short)f2bf(b.w);
  *(short8*)&o[idx * 8] = v;
}

__global__ __launch_bounds__(256) void k_cvt_transpose(const float* __restrict__ w,
                                                       short* __restrict__ wt,
                                                       int C) {
  int idx = blockIdx.x * 256 + threadIdx.x;
  int k = idx & 511;
  int n = idx >> 9;
  if (n < C) wt[n * 512 + k] = (short)f2bf(w[k * C + n]);
}

// ---------------- GEMM (128x128 tile, BK=32, 4 waves) ----------------
// MODE 0: qkv epilogue; Q pre-scaled by 0.125*log2e; K stored with 16B-chunk
// XOR swizzle (chunk' = chunk ^ (s&7)); V^T stored with column-chunk swizzle
// (chunk' = chunk ^ (hd&7) within each 64-col block). MODE 1: fp32 + bias.
template <int MODE>
__global__ __launch_bounds__(256) void k_gemm(const short* __restrict__ A,
                                              const short* __restrict__ Bt,
                                              const float* __restrict__ bias,
                                              short* __restrict__ Qo,
                                              short* __restrict__ Ko,
                                              short* __restrict__ VTo,
                                              float* __restrict__ Fo) {
  __shared__ short As[4096];
  __shared__ short Bs[4096];
  const int tid = threadIdx.x;
  const int w = tid >> 6, l = tid & 63, g = l >> 4, c = l & 15;
  const int bm = blockIdx.x * 128, bn = blockIdx.y * 128;
  const int wm = (w >> 1) * 64, wn = (w & 1) * 64;
  const int ch = w * 64 + l;
  const int ar = ch >> 2;
  const int ac = (ch & 3) * 8;
  f32x4 acc[4][4] = {};
  const short* Ap = A + (bm + ar) * 512 + ac;
  const short* Ap2 = Ap + 64 * 512;
  const short* Bp = Bt + (bn + ar) * 512 + ac;
  const short* Bp2 = Bp + 64 * 512;
  short* AsW = &As[w * 512];
  short* BsW = &Bs[w * 512];

  for (int k0 = 0; k0 < 512; k0 += 32) {
    __syncthreads();
    GLOAD_LDS16(Ap + k0, AsW);
    GLOAD_LDS16(Ap2 + k0, AsW + 2048);
    GLOAD_LDS16(Bp + k0, BsW);
    GLOAD_LDS16(Bp2 + k0, BsW + 2048);
    __syncthreads();
    short8 af[4], bfr[4];
#pragma unroll
    for (int mt = 0; mt < 4; mt++)
      af[mt] = *(const short8*)&As[(wm + mt * 16 + c) * 32 + 8 * g];
#pragma unroll
    for (int nt = 0; nt < 4; nt++)
      bfr[nt] = *(const short8*)&Bs[(wn + nt * 16 + c) * 32 + 8 * g];
#pragma unroll
    for (int mt = 0; mt < 4; mt++)
#pragma unroll
      for (int nt = 0; nt < 4; nt++)
        acc[mt][nt] = mfma16(af[mt], bfr[nt], acc[mt][nt]);
  }

  if (MODE == 0) {
    const float QS = 0.125f * 1.4426950408889634f;
#pragma unroll
    for (int nt = 0; nt < 4; nt++) {
      int n = bn + wn + nt * 16 + c;
      float bv = bias[n];
      int h = n / 192;
      int t = n - h * 192;
      int type = t >> 6;
      int hd = t & 63;
      float sc = (type == 0) ? QS : 1.0f;
#pragma unroll
      for (int mt = 0; mt < 4; mt++) {
        int m0 = bm + wm + mt * 16 + 4 * g;
        int b = m0 >> 11, s0 = m0 & 2047;
        int bh = b * 8 + h;
        if (type == 2) {
          int sw = (s0 & ~63) | (((((s0 >> 3) & 7) ^ (hd & 7)) << 3)) | (s0 & 7);
          short4v pk;
#pragma unroll
          for (int r = 0; r < 4; r++) pk[r] = (short)f2bf(acc[mt][nt][r] + bv);
          *(short4v*)&VTo[(bh * 64 + hd) * 2048 + sw] = pk;
        } else if (type == 1) {
#pragma unroll
          for (int r = 0; r < 4; r++) {
            int s = s0 + r;
            int hds = ((((hd >> 3) ^ (s & 7)) << 3)) | (hd & 7);
            Ko[(bh * 2048 + s) * 64 + hds] = (short)f2bf(acc[mt][nt][r] + bv);
          }
        } else {
#pragma unroll
          for (int r = 0; r < 4; r++)
            Qo[(bh * 2048 + s0 + r) * 64 + hd] = (short)f2bf((acc[mt][nt][r] + bv) * sc);
        }
      }
    }
  } else {
#pragma unroll
    for (int nt = 0; nt < 4; nt++) {
      int n = bn + wn + nt * 16 + c;
      float bv = bias[n];
#pragma unroll
      for (int mt = 0; mt < 4; mt++) {
        int m0 = bm + wm + mt * 16 + 4 * g;
#pragma unroll
        for (int r = 0; r < 4; r++) Fo[(m0 + r) * 512 + n] = acc[mt][nt][r] + bv;
      }
    }
  }
}

// ---------------- flash attention (single-buffer, 6 blocks/CU) ----------------
// 1024 blocks = 32 bh x 32 q-chunks (64 rows; 4 waves x 16 rows), LPT heavy-
// first. KV single-buffered in LDS (24KB total -> 6 blocks/CU = 6 waves/SIMD;
// stage latency hidden by cross-block TLP). Fixed-max softmax p = exp2(s-16)
// with -16 in the MFMA C-init; exp2 via __builtin_amdgcn_exp2f (v_exp_f32).
__global__ __launch_bounds__(256, 6) void k_attn(const short* __restrict__ Q,
                                                 const short* __restrict__ K,
                                                 const short* __restrict__ VT,
                                                 short* __restrict__ ctx) {
  __shared__ short Ks[4096];      // [64 kv][64 hd] swizzled
  __shared__ short Vs[4096];      // [64 hd][64 kv] swizzled
  __shared__ short P[4][1024];    // per-wave [16 q][64 kv] swizzled
  const int tid = threadIdx.x;
  const int w = tid >> 6, l = tid & 63, g = l >> 4, c = l & 15;

  const int x = blockIdx.x;
  const int bh = x & 31;
  const int jc = 31 - (x >> 5);    // 0..31, heaviest first
  const int qbase = jc * 64 + w * 16;
  const int ntiles = jc + 1;

  const short* Qb = Q + bh * S_ * HD_;
  const short* Kb = K + bh * S_ * HD_;
  const short* Vb = VT + bh * HD_ * S_;

  const int i0 = tid, i1 = tid + 256;
  const int kr0 = i0 >> 3, kc0 = (i0 & 7) * 8;
  const int kr1 = i1 >> 3, kc1 = (i1 & 7) * 8;
  short* KL0 = &Ks[w * 512];
  short* KL1 = &Ks[2048 + w * 512];
  short* VL0 = &Vs[w * 512];
  short* VL1 = &Vs[2048 + w * 512];

#define STAGE(kv0)                                                          \
  {                                                                         \
    GLOAD_LDS16(Kb + ((kv0) + kr0) * 64 + kc0, KL0);                        \
    GLOAD_LDS16(Kb + ((kv0) + kr1) * 64 + kc1, KL1);                        \
    GLOAD_LDS16(Vb + kr0 * 2048 + (kv0) + kc0, VL0);                        \
    GLOAD_LDS16(Vb + kr1 * 2048 + (kv0) + kc1, VL1);                        \
  }

  short* Pw = &P[w][0];
  const int bb = bh >> 3, hh = bh & 7;
  const f32x4 CINIT = {-16.f, -16.f, -16.f, -16.f};

  short8 qf0 = *(const short8*)&Qb[(qbase + c) * 64 + 8 * g];
  short8 qf1 = *(const short8*)&Qb[(qbase + c) * 64 + 8 * g + 32];

  f32x4 o[4];
  float psum[4];
#pragma unroll
  for (int nt = 0; nt < 4; nt++) o[nt] = f32x4{0.f, 0.f, 0.f, 0.f};
#pragma unroll
  for (int r = 0; r < 4; r++) psum[r] = 0.f;

  for (int it = 0; it < ntiles; ++it) {
    const int kv0 = it * 64;
    STAGE(kv0);
    __syncthreads();   // drains this wave's global_load_lds (vmcnt 0) + sync

    // QK^T from LDS (swizzle-read); C-init = -16 folds the softmax offset
    f32x4 sa[4];
#pragma unroll
    for (int nt = 0; nt < 4; nt++) {
      short8 kf0 = *(const short8*)&Ks[((nt * 16 + c) << 6) + ((g ^ (c & 7)) << 3)];
      short8 kf1 = *(const short8*)&Ks[((nt * 16 + c) << 6) + (((g + 4) ^ (c & 7)) << 3)];
      sa[nt] = mfma16(qf0, kf0, CINIT);
      sa[nt] = mfma16(qf1, kf1, sa[nt]);
    }

    // causal mask (only the diagonal tile for this wave's rows)
    if (kv0 + 64 > qbase) {
#pragma unroll
      for (int nt = 0; nt < 4; nt++) {
        int kv = kv0 + nt * 16 + c;
#pragma unroll
        for (int r = 0; r < 4; r++) {
          int qrow = qbase + 4 * g + r;
          if (kv > qrow) sa[nt][r] = -1e30f;
        }
      }
    }

    // p = exp2(s) via raw v_exp_f32; partial row sums; pack to swizzled P
#pragma unroll
    for (int nt = 0; nt < 4; nt++)
#pragma unroll
      for (int r = 0; r < 4; r++) {
        float pv = __builtin_amdgcn_exp2f(sa[nt][r]);
        psum[r] += pv;
        int row = 4 * g + r;
        int col = nt * 16 + c;
        int off = (row << 6) + ((((col >> 3) ^ (row & 7)) << 3)) + (col & 7);
        Pw[off] = (short)f2bf(pv);
      }

    // PV from LDS P and V (swizzle-read)
#pragma unroll
    for (int kvb = 0; kvb < 2; kvb++) {
      short8 pa = *(const short8*)&Pw[(c << 6) + (((kvb * 4 + g) ^ (c & 7)) << 3)];
#pragma unroll
      for (int nt = 0; nt < 4; nt++) {
        short8 vb = *(const short8*)&Vs[((nt * 16 + c) << 6) +
                                        (((kvb * 4 + g) ^ (c & 7)) << 3)];
        o[nt] = mfma16(pa, vb, o[nt]);
      }
    }

    __syncthreads();   // all waves done reading before next STAGE overwrites
  }

  // row-sum reduce over the 16 c-lanes in each g-group
#pragma unroll
  for (int off = 1; off < 16; off <<= 1)
#pragma unroll
    for (int r = 0; r < 4; r++) psum[r] += __shfl_xor(psum[r], off, 64);

  float inv[4];
#pragma unroll
  for (int r = 0; r < 4; r++) inv[r] = 1.0f / psum[r];
#pragma unroll
  for (int nt = 0; nt < 4; nt++)
#pragma unroll
    for (int r = 0; r < 4; r++) {
      int srow = qbase + 4 * g + r;
      ctx[(bb * S_ + srow) * 512 + hh * 64 + nt * 16 + c] =
          (short)f2bf(o[nt][r] * inv[r]);
    }
#undef STAGE
}

// ---------------- launcher ----------------

extern "C" void kernel_launch(void* const* d_in, const int* in_sizes, int n_in,
                              void* d_out, int out_size, void* d_ws, size_t ws_size,
                              hipStream_t stream) {
  const float* x = (const float*)d_in[0];
  const float* Wqkv = (const float*)d_in[2];
  const float* bqkv = (const float*)d_in[3];
  const float* Wo = (const float*)d_in[4];
  const float* bo = (const float*)d_in[5];
  float* out = (float*)d_out;

  char* ws = (char*)d_ws;
  short* xb    = (short*)(ws + 0);
  short* wqkvt = (short*)(ws + 8388608);
  short* wot   = (short*)(ws + 9961472);
  short* Qw    = (short*)(ws + 10485760);
  short* Kw    = (short*)(ws + 18874368);
  short* VTw   = (short*)(ws + 27262976);
  short* ctx   = (short*)(ws + 35651584);

  k_cvt_bf16x8<<<2048, 256, 0, stream>>>(x, xb);
  k_cvt_transpose<<<3072, 256, 0, stream>>>(Wqkv, wqkvt, 1536);
  k_cvt_transpose<<<1024, 256, 0, stream>>>(Wo, wot, 512);

  dim3 g1(64, 12);
  k_gemm<0><<<g1, 256, 0, stream>>>(xb, wqkvt, bqkv, Qw, Kw, VTw, nullptr);

  k_attn<<<1024, 256, 0, stream>>>(Qw, Kw, VTw, ctx);

  dim3 g3(64, 4);
  k_gemm<1><<<g3, 256, 0, stream>>>(ctx, wot, bo, nullptr, nullptr, nullptr, out);
}

// Round 10
// 94.087 us; speedup vs baseline: 1.3705x; 1.3705x over previous
//
#include <hip/hip_runtime.h>
#include <hip/hip_bf16.h>

#define S_ 2048
#define D_ 512
#define HD_ 64
#define HH_ 8
#define M_ 8192

typedef __attribute__((ext_vector_type(8))) short short8;
typedef __attribute__((ext_vector_type(4))) short short4v;
typedef __attribute__((ext_vector_type(4))) float f32x4;

__device__ __forceinline__ unsigned short f2bf(float f) {
  unsigned u = __builtin_bit_cast(unsigned, f);
  u += 0x7fffu + ((u >> 16) & 1u);
  return (unsigned short)(u >> 16);
}

__device__ __forceinline__ f32x4 mfma16(short8 a, short8 b, f32x4 c) {
  return __builtin_amdgcn_mfma_f32_16x16x32_bf16(a, b, c, 0, 0, 0);
}

#define GLOAD_LDS16(gp, lp)                                                        \
  __builtin_amdgcn_global_load_lds(                                                \
      (const __attribute__((address_space(1))) void*)(gp),                         \
      (__attribute__((address_space(3))) void*)(lp), 16, 0, 0)

// ---------------- converts ----------------

__global__ __launch_bounds__(256) void k_cvt_bf16x8(const float* __restrict__ x,
                                                    short* __restrict__ o) {
  int idx = blockIdx.x * 256 + threadIdx.x;
  const float4* p = (const float4*)x;
  float4 a = p[idx * 2];
  float4 b = p[idx * 2 + 1];
  short8 v;
  v[0] = (short)f2bf(a.x); v[1] = (short)f2bf(a.y);
  v[2] = (short)f2bf(a.z); v[3] = (short)f2bf(a.w);
  v[4] = (short)f2bf(b.x); v[5] = (short)f2bf(b.y);
  v[6] = (short)f2bf(b.z); v[7] = (short)f2bf(b.w);
  *(short8*)&o[idx * 8] = v;
}

// LDS-tiled transpose: wt[n][k] = bf16(w[k][n]); w is [512][C].
// Block does a 32x32 tile; coalesced read AND write.
__global__ __launch_bounds__(256) void k_cvt_transpose(const float* __restrict__ w,
                                                       short* __restrict__ wt,
                                                       int C) {
  __shared__ short T[32][33];
  const int tx = threadIdx.x & 31, ty = threadIdx.x >> 5;  // 32 x 8
  const int n0 = blockIdx.x * 32, k0 = blockIdx.y * 32;
#pragma unroll
  for (int i = 0; i < 4; i++) {
    int k = k0 + ty + 8 * i;
    T[ty + 8 * i][tx] = (short)f2bf(w[k * C + n0 + tx]);
  }
  __syncthreads();
#pragma unroll
  for (int i = 0; i < 4; i++) {
    int n = n0 + ty + 8 * i;
    wt[n * 512 + k0 + tx] = T[tx][ty + 8 * i];
  }
}

// ---------------- GEMM (128x128 tile, BK=32, 4 waves) ----------------
// MODE 0: qkv epilogue; Q pre-scaled by 0.125*log2e; K stored with 16B-chunk
// XOR swizzle (chunk' = chunk ^ (s&7)); V^T stored with column-chunk swizzle
// (chunk' = chunk ^ (hd&7) within each 64-col block). MODE 1: fp32 + bias.
template <int MODE>
__global__ __launch_bounds__(256) void k_gemm(const short* __restrict__ A,
                                              const short* __restrict__ Bt,
                                              const float* __restrict__ bias,
                                              short* __restrict__ Qo,
                                              short* __restrict__ Ko,
                                              short* __restrict__ VTo,
                                              float* __restrict__ Fo) {
  __shared__ short As[4096];
  __shared__ short Bs[4096];
  const int tid = threadIdx.x;
  const int w = tid >> 6, l = tid & 63, g = l >> 4, c = l & 15;
  const int bm = blockIdx.x * 128, bn = blockIdx.y * 128;
  const int wm = (w >> 1) * 64, wn = (w & 1) * 64;
  const int ch = w * 64 + l;
  const int ar = ch >> 2;
  const int ac = (ch & 3) * 8;
  f32x4 acc[4][4] = {};
  const short* Ap = A + (bm + ar) * 512 + ac;
  const short* Ap2 = Ap + 64 * 512;
  const short* Bp = Bt + (bn + ar) * 512 + ac;
  const short* Bp2 = Bp + 64 * 512;
  short* AsW = &As[w * 512];
  short* BsW = &Bs[w * 512];

  for (int k0 = 0; k0 < 512; k0 += 32) {
    __syncthreads();
    GLOAD_LDS16(Ap + k0, AsW);
    GLOAD_LDS16(Ap2 + k0, AsW + 2048);
    GLOAD_LDS16(Bp + k0, BsW);
    GLOAD_LDS16(Bp2 + k0, BsW + 2048);
    __syncthreads();
    short8 af[4], bfr[4];
#pragma unroll
    for (int mt = 0; mt < 4; mt++)
      af[mt] = *(const short8*)&As[(wm + mt * 16 + c) * 32 + 8 * g];
#pragma unroll
    for (int nt = 0; nt < 4; nt++)
      bfr[nt] = *(const short8*)&Bs[(wn + nt * 16 + c) * 32 + 8 * g];
#pragma unroll
    for (int mt = 0; mt < 4; mt++)
#pragma unroll
      for (int nt = 0; nt < 4; nt++)
        acc[mt][nt] = mfma16(af[mt], bfr[nt], acc[mt][nt]);
  }

  if (MODE == 0) {
    const float QS = 0.125f * 1.4426950408889634f;
#pragma unroll
    for (int nt = 0; nt < 4; nt++) {
      int n = bn + wn + nt * 16 + c;
      float bv = bias[n];
      int h = n / 192;
      int t = n - h * 192;
      int type = t >> 6;
      int hd = t & 63;
      float sc = (type == 0) ? QS : 1.0f;
#pragma unroll
      for (int mt = 0; mt < 4; mt++) {
        int m0 = bm + wm + mt * 16 + 4 * g;
        int b = m0 >> 11, s0 = m0 & 2047;
        int bh = b * 8 + h;
        if (type == 2) {
          int sw = (s0 & ~63) | (((((s0 >> 3) & 7) ^ (hd & 7)) << 3)) | (s0 & 7);
          short4v pk;
#pragma unroll
          for (int r = 0; r < 4; r++) pk[r] = (short)f2bf(acc[mt][nt][r] + bv);
          *(short4v*)&VTo[(bh * 64 + hd) * 2048 + sw] = pk;
        } else if (type == 1) {
#pragma unroll
          for (int r = 0; r < 4; r++) {
            int s = s0 + r;
            int hds = ((((hd >> 3) ^ (s & 7)) << 3)) | (hd & 7);
            Ko[(bh * 2048 + s) * 64 + hds] = (short)f2bf(acc[mt][nt][r] + bv);
          }
        } else {
#pragma unroll
          for (int r = 0; r < 4; r++)
            Qo[(bh * 2048 + s0 + r) * 64 + hd] = (short)f2bf((acc[mt][nt][r] + bv) * sc);
        }
      }
    }
  } else {
#pragma unroll
    for (int nt = 0; nt < 4; nt++) {
      int n = bn + wn + nt * 16 + c;
      float bv = bias[n];
#pragma unroll
      for (int mt = 0; mt < 4; mt++) {
        int m0 = bm + wm + mt * 16 + 4 * g;
#pragma unroll
        for (int r = 0; r < 4; r++) Fo[(m0 + r) * 512 + n] = acc[mt][nt][r] + bv;
      }
    }
  }
}

// ---------------- flash attention (double-buffered, exp2-builtin) ----------------
// 1024 blocks = 32 bh x 32 q-chunks (64 rows; 4 waves x 16 rows), LPT heavy-
// first. KV double-buffered LDS (40KB, 4 blocks/CU). STAGE(next) issued at
// iter top, drained by the end-of-iter barrier (latency hidden under compute).
// Fixed-max softmax p = exp2(s-16), -16 in MFMA C-init, raw v_exp_f32.
__global__ __launch_bounds__(256, 4) void k_attn(const short* __restrict__ Q,
                                                 const short* __restrict__ K,
                                                 const short* __restrict__ VT,
                                                 short* __restrict__ ctx) {
  __shared__ short Ks[2][4096];   // [64 kv][64 hd] swizzled
  __shared__ short Vs[2][4096];   // [64 hd][64 kv] swizzled
  __shared__ short P[4][1024];    // per-wave [16 q][64 kv] swizzled
  const int tid = threadIdx.x;
  const int w = tid >> 6, l = tid & 63, g = l >> 4, c = l & 15;

  const int x = blockIdx.x;
  const int bh = x & 31;
  const int jc = 31 - (x >> 5);    // 0..31, heaviest first
  const int qbase = jc * 64 + w * 16;
  const int ntiles = jc + 1;

  const short* Qb = Q + bh * S_ * HD_;
  const short* Kb = K + bh * S_ * HD_;
  const short* Vb = VT + bh * HD_ * S_;

  const int i0 = tid, i1 = tid + 256;
  const int kr0 = i0 >> 3, kc0 = (i0 & 7) * 8;
  const int kr1 = i1 >> 3, kc1 = (i1 & 7) * 8;
  short* KL0 = &Ks[0][w * 512];
  short* KL1 = &Ks[0][2048 + w * 512];
  short* VL0 = &Vs[0][w * 512];
  short* VL1 = &Vs[0][2048 + w * 512];

#define STAGE(buf, kv0)                                                     \
  {                                                                         \
    GLOAD_LDS16(Kb + ((kv0) + kr0) * 64 + kc0, KL0 + (buf)*4096);           \
    GLOAD_LDS16(Kb + ((kv0) + kr1) * 64 + kc1, KL1 + (buf)*4096);           \
    GLOAD_LDS16(Vb + kr0 * 2048 + (kv0) + kc0, VL0 + (buf)*4096);           \
    GLOAD_LDS16(Vb + kr1 * 2048 + (kv0) + kc1, VL1 + (buf)*4096);           \
  }

  short* Pw = &P[w][0];
  const int bb = bh >> 3, hh = bh & 7;
  const f32x4 CINIT = {-16.f, -16.f, -16.f, -16.f};

  short8 qf0 = *(const short8*)&Qb[(qbase + c) * 64 + 8 * g];
  short8 qf1 = *(const short8*)&Qb[(qbase + c) * 64 + 8 * g + 32];

  f32x4 o[4];
  float psum[4];
#pragma unroll
  for (int nt = 0; nt < 4; nt++) o[nt] = f32x4{0.f, 0.f, 0.f, 0.f};
#pragma unroll
  for (int r = 0; r < 4; r++) psum[r] = 0.f;

  STAGE(0, 0);
  __syncthreads();

  int cur = 0;
  for (int it = 0; it < ntiles; ++it) {
    const int kv0 = it * 64;
    if (it + 1 < ntiles) STAGE(cur ^ 1, kv0 + 64);

    const short* Kt = &Ks[cur][0];
    const short* Vt = &Vs[cur][0];

    // QK^T from LDS (swizzle-read); C-init = -16 folds the softmax offset
    f32x4 sa[4];
#pragma unroll
    for (int nt = 0; nt < 4; nt++) {
      short8 kf0 = *(const short8*)&Kt[((nt * 16 + c) << 6) + ((g ^ (c & 7)) << 3)];
      short8 kf1 = *(const short8*)&Kt[((nt * 16 + c) << 6) + (((g + 4) ^ (c & 7)) << 3)];
      sa[nt] = mfma16(qf0, kf0, CINIT);
      sa[nt] = mfma16(qf1, kf1, sa[nt]);
    }

    // causal mask (only the diagonal tile for this wave's rows)
    if (kv0 + 64 > qbase) {
#pragma unroll
      for (int nt = 0; nt < 4; nt++) {
        int kv = kv0 + nt * 16 + c;
#pragma unroll
        for (int r = 0; r < 4; r++) {
          int qrow = qbase + 4 * g + r;
          if (kv > qrow) sa[nt][r] = -1e30f;
        }
      }
    }

    // p = exp2(s) via raw v_exp_f32; partial row sums; pack to swizzled P
#pragma unroll
    for (int nt = 0; nt < 4; nt++)
#pragma unroll
      for (int r = 0; r < 4; r++) {
        float pv = __builtin_amdgcn_exp2f(sa[nt][r]);
        psum[r] += pv;
        int row = 4 * g + r;
        int col = nt * 16 + c;
        int off = (row << 6) + ((((col >> 3) ^ (row & 7)) << 3)) + (col & 7);
        Pw[off] = (short)f2bf(pv);
      }

    // PV from LDS P and V (swizzle-read)
#pragma unroll
    for (int kvb = 0; kvb < 2; kvb++) {
      short8 pa = *(const short8*)&Pw[(c << 6) + (((kvb * 4 + g) ^ (c & 7)) << 3)];
#pragma unroll
      for (int nt = 0; nt < 4; nt++) {
        short8 vb = *(const short8*)&Vt[((nt * 16 + c) << 6) +
                                        (((kvb * 4 + g) ^ (c & 7)) << 3)];
        o[nt] = mfma16(pa, vb, o[nt]);
      }
    }

    __syncthreads();   // drains this iter's STAGE (vmcnt 0) + buffer swap sync
    cur ^= 1;
  }

  // row-sum reduce over the 16 c-lanes in each g-group
#pragma unroll
  for (int off = 1; off < 16; off <<= 1)
#pragma unroll
    for (int r = 0; r < 4; r++) psum[r] += __shfl_xor(psum[r], off, 64);

  float inv[4];
#pragma unroll
  for (int r = 0; r < 4; r++) inv[r] = 1.0f / psum[r];
#pragma unroll
  for (int nt = 0; nt < 4; nt++)
#pragma unroll
    for (int r = 0; r < 4; r++) {
      int srow = qbase + 4 * g + r;
      ctx[(bb * S_ + srow) * 512 + hh * 64 + nt * 16 + c] =
          (short)f2bf(o[nt][r] * inv[r]);
    }
#undef STAGE
}

// ---------------- launcher ----------------

extern "C" void kernel_launch(void* const* d_in, const int* in_sizes, int n_in,
                              void* d_out, int out_size, void* d_ws, size_t ws_size,
                              hipStream_t stream) {
  const float* x = (const float*)d_in[0];
  const float* Wqkv = (const float*)d_in[2];
  const float* bqkv = (const float*)d_in[3];
  const float* Wo = (const float*)d_in[4];
  const float* bo = (const float*)d_in[5];
  float* out = (float*)d_out;

  char* ws = (char*)d_ws;
  short* xb    = (short*)(ws + 0);
  short* wqkvt = (short*)(ws + 8388608);
  short* wot   = (short*)(ws + 9961472);
  short* Qw    = (short*)(ws + 10485760);
  short* Kw    = (short*)(ws + 18874368);
  short* VTw   = (short*)(ws + 27262976);
  short* ctx   = (short*)(ws + 35651584);

  k_cvt_bf16x8<<<2048, 256, 0, stream>>>(x, xb);
  {
    dim3 gt(48, 16);
    k_cvt_transpose<<<gt, 256, 0, stream>>>(Wqkv, wqkvt, 1536);
    dim3 gt2(16, 16);
    k_cvt_transpose<<<gt2, 256, 0, stream>>>(Wo, wot, 512);
  }

  dim3 g1(64, 12);
  k_gemm<0><<<g1, 256, 0, stream>>>(xb, wqkvt, bqkv, Qw, Kw, VTw, nullptr);

  k_attn<<<1024, 256, 0, stream>>>(Qw, Kw, VTw, ctx);

  dim3 g3(64, 4);
  k_gemm<1><<<g3, 256, 0, stream>>>(ctx, wot, bo, nullptr, nullptr, nullptr, out);
}

// Round 11
// 88.787 us; speedup vs baseline: 1.4524x; 1.0597x over previous
//
#include <hip/hip_runtime.h>
#include <hip/hip_bf16.h>

#define S_ 2048
#define D_ 512
#define HD_ 64
#define HH_ 8
#define M_ 8192

typedef __attribute__((ext_vector_type(8))) short short8;
typedef __attribute__((ext_vector_type(4))) short short4v;
typedef __attribute__((ext_vector_type(4))) float f32x4;

__device__ __forceinline__ unsigned short f2bf(float f) {
  unsigned u = __builtin_bit_cast(unsigned, f);
  u += 0x7fffu + ((u >> 16) & 1u);
  return (unsigned short)(u >> 16);
}

__device__ __forceinline__ f32x4 mfma16(short8 a, short8 b, f32x4 c) {
  return __builtin_amdgcn_mfma_f32_16x16x32_bf16(a, b, c, 0, 0, 0);
}

#define GLOAD_LDS16(gp, lp)                                                        \
  __builtin_amdgcn_global_load_lds(                                                \
      (const __attribute__((address_space(1))) void*)(gp),                         \
      (__attribute__((address_space(3))) void*)(lp), 16, 0, 0)

// ---------------- converts ----------------
// x -> bf16, stored ROW-SWIZZLED for GEMM staging: within each 64-short group,
// 16B chunk ch holds data chunk ch^(row&7)  (read side XORs the same way).
__global__ __launch_bounds__(256) void k_cvt_bf16x8(const float* __restrict__ x,
                                                    short* __restrict__ o) {
  int idx = blockIdx.x * 256 + threadIdx.x;
  const float4* p = (const float4*)x;
  float4 a = p[idx * 2];
  float4 b = p[idx * 2 + 1];
  short8 v;
  v[0] = (short)f2bf(a.x); v[1] = (short)f2bf(a.y);
  v[2] = (short)f2bf(a.z); v[3] = (short)f2bf(a.w);
  v[4] = (short)f2bf(b.x); v[5] = (short)f2bf(b.y);
  v[6] = (short)f2bf(b.z); v[7] = (short)f2bf(b.w);
  int row = idx >> 6;
  int dst = row * 512 + ((idx >> 3) & 7) * 64 + (((idx & 7) ^ (row & 7)) << 3);
  *(short8*)&o[dst] = v;
}

// LDS-tiled transpose + swizzle: wt[n][ksw] = bf16(w[k][n]), w is [512][C];
// ksw applies the same per-row (n) chunk XOR swizzle for GEMM staging.
__global__ __launch_bounds__(256) void k_cvt_transpose(const float* __restrict__ w,
                                                       short* __restrict__ wt,
                                                       int C) {
  __shared__ short T[32][33];
  const int tx = threadIdx.x & 31, ty = threadIdx.x >> 5;  // 32 x 8
  const int n0 = blockIdx.x * 32, k0 = blockIdx.y * 32;
#pragma unroll
  for (int i = 0; i < 4; i++) {
    int k = k0 + ty + 8 * i;
    T[ty + 8 * i][tx] = (short)f2bf(w[k * C + n0 + tx]);
  }
  __syncthreads();
#pragma unroll
  for (int i = 0; i < 4; i++) {
    int n = n0 + ty + 8 * i;
    int k = k0 + tx;
    int ksw = (k & ~63) | ((((k >> 3) & 7) ^ (n & 7)) << 3) | (k & 7);
    wt[n * 512 + ksw] = T[tx][ty + 8 * i];
  }
}

// ---------------- GEMM (128x128 tile, BK=64, pipelined, swizzled LDS) -------
// Inputs A, Bt are pre-swizzled in global (chunk ^= row&7 per 64-col group) so
// linear global_load_lds staging yields the conflict-free XOR layout; reads
// XOR with (c&7) -- proven pattern from the attention K-tile. Single barrier
// per K-step: STAGE(next) issued before compute, drained by end barrier.
// MODE 0: qkv epilogue (Q pre-scaled, K/VT attn-swizzled). MODE 1: fp32+bias.
template <int MODE>
__global__ __launch_bounds__(256) void k_gemm(const short* __restrict__ A,
                                              const short* __restrict__ Bt,
                                              const float* __restrict__ bias,
                                              short* __restrict__ Qo,
                                              short* __restrict__ Ko,
                                              short* __restrict__ VTo,
                                              float* __restrict__ Fo) {
  __shared__ short As[2][8192];  // [128][64] swizzled
  __shared__ short Bs[2][8192];
  const int tid = threadIdx.x;
  const int w = tid >> 6, l = tid & 63, g = l >> 4, c = l & 15;
  const int bm = blockIdx.x * 128, bn = blockIdx.y * 128;
  const int wm = (w >> 1) * 64, wn = (w & 1) * 64;
  f32x4 acc[4][4] = {};
  const int sr = l >> 3, sc8 = (l & 7) * 8;
  const short* Ap = A + (bm + sr) * 512 + sc8;
  const short* Bp = Bt + (bn + sr) * 512 + sc8;
  const int s0 = w * 4;  // this wave's 4 segments (8 rows each)

#define GSTAGE(buf, k0)                                                      \
  {                                                                          \
    GLOAD_LDS16(Ap + (s0 + 0) * 4096 + (k0), &As[buf][(s0 + 0) * 512]);      \
    GLOAD_LDS16(Ap + (s0 + 1) * 4096 + (k0), &As[buf][(s0 + 1) * 512]);     \
    GLOAD_LDS16(Ap + (s0 + 2) * 4096 + (k0), &As[buf][(s0 + 2) * 512]);     \
    GLOAD_LDS16(Ap + (s0 + 3) * 4096 + (k0), &As[buf][(s0 + 3) * 512]);     \
    GLOAD_LDS16(Bp + (s0 + 0) * 4096 + (k0), &Bs[buf][(s0 + 0) * 512]);     \
    GLOAD_LDS16(Bp + (s0 + 1) * 4096 + (k0), &Bs[buf][(s0 + 1) * 512]);     \
    GLOAD_LDS16(Bp + (s0 + 2) * 4096 + (k0), &Bs[buf][(s0 + 2) * 512]);     \
    GLOAD_LDS16(Bp + (s0 + 3) * 4096 + (k0), &Bs[buf][(s0 + 3) * 512]);     \
  }

  GSTAGE(0, 0);
  __syncthreads();

  const int cs = c & 7;
  int cur = 0;
  for (int k0 = 0; k0 < 512; k0 += 64) {
    if (k0 + 64 < 512) GSTAGE(cur ^ 1, k0 + 64);

    short8 a0[4], a1[4], b0[4], b1[4];
#pragma unroll
    for (int mt = 0; mt < 4; mt++) {
      const short* r = &As[cur][(wm + mt * 16 + c) * 64];
      a0[mt] = *(const short8*)&r[(g ^ cs) << 3];
      a1[mt] = *(const short8*)&r[((g + 4) ^ cs) << 3];
    }
#pragma unroll
    for (int nt = 0; nt < 4; nt++) {
      const short* r = &Bs[cur][(wn + nt * 16 + c) * 64];
      b0[nt] = *(const short8*)&r[(g ^ cs) << 3];
      b1[nt] = *(const short8*)&r[((g + 4) ^ cs) << 3];
    }
#pragma unroll
    for (int mt = 0; mt < 4; mt++)
#pragma unroll
      for (int nt = 0; nt < 4; nt++) {
        acc[mt][nt] = mfma16(a0[mt], b0[nt], acc[mt][nt]);
        acc[mt][nt] = mfma16(a1[mt], b1[nt], acc[mt][nt]);
      }

    __syncthreads();   // drains GSTAGE (vmcnt 0) + read/write buffer sync
    cur ^= 1;
  }
#undef GSTAGE

  if (MODE == 0) {
    const float QS = 0.125f * 1.4426950408889634f;
#pragma unroll
    for (int nt = 0; nt < 4; nt++) {
      int n = bn + wn + nt * 16 + c;
      float bv = bias[n];
      int h = n / 192;
      int t = n - h * 192;
      int type = t >> 6;
      int hd = t & 63;
      float sc = (type == 0) ? QS : 1.0f;
#pragma unroll
      for (int mt = 0; mt < 4; mt++) {
        int m0 = bm + wm + mt * 16 + 4 * g;
        int b = m0 >> 11, ss = m0 & 2047;
        int bh = b * 8 + h;
        if (type == 2) {
          int sw = (ss & ~63) | (((((ss >> 3) & 7) ^ (hd & 7)) << 3)) | (ss & 7);
          short4v pk;
#pragma unroll
          for (int r = 0; r < 4; r++) pk[r] = (short)f2bf(acc[mt][nt][r] + bv);
          *(short4v*)&VTo[(bh * 64 + hd) * 2048 + sw] = pk;
        } else if (type == 1) {
#pragma unroll
          for (int r = 0; r < 4; r++) {
            int s = ss + r;
            int hds = ((((hd >> 3) ^ (s & 7)) << 3)) | (hd & 7);
            Ko[(bh * 2048 + s) * 64 + hds] = (short)f2bf(acc[mt][nt][r] + bv);
          }
        } else {
#pragma unroll
          for (int r = 0; r < 4; r++)
            Qo[(bh * 2048 + ss + r) * 64 + hd] = (short)f2bf((acc[mt][nt][r] + bv) * sc);
        }
      }
    }
  } else {
#pragma unroll
    for (int nt = 0; nt < 4; nt++) {
      int n = bn + wn + nt * 16 + c;
      float bv = bias[n];
#pragma unroll
      for (int mt = 0; mt < 4; mt++) {
        int m0 = bm + wm + mt * 16 + 4 * g;
#pragma unroll
        for (int r = 0; r < 4; r++) Fo[(m0 + r) * 512 + n] = acc[mt][nt][r] + bv;
      }
    }
  }
}

// ---------------- flash attention (double-buffered, exp2-builtin) ----------------
// Unchanged from round 10 except the ctx store applies the GEMM-staging row
// swizzle (ctx is consumed by the MODE-1 GEMM's linear global_load_lds).
__global__ __launch_bounds__(256, 4) void k_attn(const short* __restrict__ Q,
                                                 const short* __restrict__ K,
                                                 const short* __restrict__ VT,
                                                 short* __restrict__ ctx) {
  __shared__ short Ks[2][4096];   // [64 kv][64 hd] swizzled
  __shared__ short Vs[2][4096];   // [64 hd][64 kv] swizzled
  __shared__ short P[4][1024];    // per-wave [16 q][64 kv] swizzled
  const int tid = threadIdx.x;
  const int w = tid >> 6, l = tid & 63, g = l >> 4, c = l & 15;

  const int x = blockIdx.x;
  const int bh = x & 31;
  const int jc = 31 - (x >> 5);    // 0..31, heaviest first
  const int qbase = jc * 64 + w * 16;
  const int ntiles = jc + 1;

  const short* Qb = Q + bh * S_ * HD_;
  const short* Kb = K + bh * S_ * HD_;
  const short* Vb = VT + bh * HD_ * S_;

  const int i0 = tid, i1 = tid + 256;
  const int kr0 = i0 >> 3, kc0 = (i0 & 7) * 8;
  const int kr1 = i1 >> 3, kc1 = (i1 & 7) * 8;
  short* KL0 = &Ks[0][w * 512];
  short* KL1 = &Ks[0][2048 + w * 512];
  short* VL0 = &Vs[0][w * 512];
  short* VL1 = &Vs[0][2048 + w * 512];

#define STAGE(buf, kv0)                                                     \
  {                                                                         \
    GLOAD_LDS16(Kb + ((kv0) + kr0) * 64 + kc0, KL0 + (buf)*4096);           \
    GLOAD_LDS16(Kb + ((kv0) + kr1) * 64 + kc1, KL1 + (buf)*4096);           \
    GLOAD_LDS16(Vb + kr0 * 2048 + (kv0) + kc0, VL0 + (buf)*4096);           \
    GLOAD_LDS16(Vb + kr1 * 2048 + (kv0) + kc1, VL1 + (buf)*4096);           \
  }

  short* Pw = &P[w][0];
  const int bb = bh >> 3, hh = bh & 7;
  const f32x4 CINIT = {-16.f, -16.f, -16.f, -16.f};

  short8 qf0 = *(const short8*)&Qb[(qbase + c) * 64 + 8 * g];
  short8 qf1 = *(const short8*)&Qb[(qbase + c) * 64 + 8 * g + 32];

  f32x4 o[4];
  float psum[4];
#pragma unroll
  for (int nt = 0; nt < 4; nt++) o[nt] = f32x4{0.f, 0.f, 0.f, 0.f};
#pragma unroll
  for (int r = 0; r < 4; r++) psum[r] = 0.f;

  STAGE(0, 0);
  __syncthreads();

  int cur = 0;
  for (int it = 0; it < ntiles; ++it) {
    const int kv0 = it * 64;
    if (it + 1 < ntiles) STAGE(cur ^ 1, kv0 + 64);

    const short* Kt = &Ks[cur][0];
    const short* Vt = &Vs[cur][0];

    // QK^T from LDS (swizzle-read); C-init = -16 folds the softmax offset
    f32x4 sa[4];
#pragma unroll
    for (int nt = 0; nt < 4; nt++) {
      short8 kf0 = *(const short8*)&Kt[((nt * 16 + c) << 6) + ((g ^ (c & 7)) << 3)];
      short8 kf1 = *(const short8*)&Kt[((nt * 16 + c) << 6) + (((g + 4) ^ (c & 7)) << 3)];
      sa[nt] = mfma16(qf0, kf0, CINIT);
      sa[nt] = mfma16(qf1, kf1, sa[nt]);
    }

    // causal mask (only the diagonal tile for this wave's rows)
    if (kv0 + 64 > qbase) {
#pragma unroll
      for (int nt = 0; nt < 4; nt++) {
        int kv = kv0 + nt * 16 + c;
#pragma unroll
        for (int r = 0; r < 4; r++) {
          int qrow = qbase + 4 * g + r;
          if (kv > qrow) sa[nt][r] = -1e30f;
        }
      }
    }

    // p = exp2(s) via raw v_exp_f32; partial row sums; pack to swizzled P
#pragma unroll
    for (int nt = 0; nt < 4; nt++)
#pragma unroll
      for (int r = 0; r < 4; r++) {
        float pv = __builtin_amdgcn_exp2f(sa[nt][r]);
        psum[r] += pv;
        int row = 4 * g + r;
        int col = nt * 16 + c;
        int off = (row << 6) + ((((col >> 3) ^ (row & 7)) << 3)) + (col & 7);
        Pw[off] = (short)f2bf(pv);
      }

    // PV from LDS P and V (swizzle-read)
#pragma unroll
    for (int kvb = 0; kvb < 2; kvb++) {
      short8 pa = *(const short8*)&Pw[(c << 6) + (((kvb * 4 + g) ^ (c & 7)) << 3)];
#pragma unroll
      for (int nt = 0; nt < 4; nt++) {
        short8 vb = *(const short8*)&Vt[((nt * 16 + c) << 6) +
                                        (((kvb * 4 + g) ^ (c & 7)) << 3)];
        o[nt] = mfma16(pa, vb, o[nt]);
      }
    }

    __syncthreads();   // drains this iter's STAGE (vmcnt 0) + buffer swap sync
    cur ^= 1;
  }

  // row-sum reduce over the 16 c-lanes in each g-group
#pragma unroll
  for (int off = 1; off < 16; off <<= 1)
#pragma unroll
    for (int r = 0; r < 4; r++) psum[r] += __shfl_xor(psum[r], off, 64);

  float inv[4];
#pragma unroll
  for (int r = 0; r < 4; r++) inv[r] = 1.0f / psum[r];
#pragma unroll
  for (int nt = 0; nt < 4; nt++)
#pragma unroll
    for (int r = 0; r < 4; r++) {
      int srow = qbase + 4 * g + r;
      int colsw = hh * 64 + (((nt * 2 + (c >> 3)) ^ (srow & 7)) << 3) + (c & 7);
      ctx[(bb * S_ + srow) * 512 + colsw] = (short)f2bf(o[nt][r] * inv[r]);
    }
#undef STAGE
}

// ---------------- launcher ----------------

extern "C" void kernel_launch(void* const* d_in, const int* in_sizes, int n_in,
                              void* d_out, int out_size, void* d_ws, size_t ws_size,
                              hipStream_t stream) {
  const float* x = (const float*)d_in[0];
  const float* Wqkv = (const float*)d_in[2];
  const float* bqkv = (const float*)d_in[3];
  const float* Wo = (const float*)d_in[4];
  const float* bo = (const float*)d_in[5];
  float* out = (float*)d_out;

  char* ws = (char*)d_ws;
  short* xb    = (short*)(ws + 0);
  short* wqkvt = (short*)(ws + 8388608);
  short* wot   = (short*)(ws + 9961472);
  short* Qw    = (short*)(ws + 10485760);
  short* Kw    = (short*)(ws + 18874368);
  short* VTw   = (short*)(ws + 27262976);
  short* ctx   = (short*)(ws + 35651584);

  k_cvt_bf16x8<<<2048, 256, 0, stream>>>(x, xb);
  {
    dim3 gt(48, 16);
    k_cvt_transpose<<<gt, 256, 0, stream>>>(Wqkv, wqkvt, 1536);
    dim3 gt2(16, 16);
    k_cvt_transpose<<<gt2, 256, 0, stream>>>(Wo, wot, 512);
  }

  dim3 g1(64, 12);
  k_gemm<0><<<g1, 256, 0, stream>>>(xb, wqkvt, bqkv, Qw, Kw, VTw, nullptr);

  k_attn<<<1024, 256, 0, stream>>>(Qw, Kw, VTw, ctx);

  dim3 g3(64, 4);
  k_gemm<1><<<g3, 256, 0, stream>>>(ctx, wot, bo, nullptr, nullptr, nullptr, out);
}

// Round 12
// 85.229 us; speedup vs baseline: 1.5130x; 1.0418x over previous
//
#include <hip/hip_runtime.h>
#include <hip/hip_bf16.h>

#define S_ 2048
#define D_ 512
#define HD_ 64
#define HH_ 8
#define M_ 8192

typedef __attribute__((ext_vector_type(8))) short short8;
typedef __attribute__((ext_vector_type(4))) short short4v;
typedef __attribute__((ext_vector_type(4))) float f32x4;

__device__ __forceinline__ unsigned short f2bf(float f) {
  unsigned u = __builtin_bit_cast(unsigned, f);
  u += 0x7fffu + ((u >> 16) & 1u);
  return (unsigned short)(u >> 16);
}

__device__ __forceinline__ f32x4 mfma16(short8 a, short8 b, f32x4 c) {
  return __builtin_amdgcn_mfma_f32_16x16x32_bf16(a, b, c, 0, 0, 0);
}

#define GLOAD_LDS16(gp, lp)                                                        \
  __builtin_amdgcn_global_load_lds(                                                \
      (const __attribute__((address_space(1))) void*)(gp),                         \
      (__attribute__((address_space(3))) void*)(lp), 16, 0, 0)

// ---------------- converts ----------------
// x -> bf16, stored ROW-SWIZZLED for GEMM staging: within each 64-short group,
// 16B chunk ch holds data chunk ch^(row&7)  (read side XORs the same way).
__global__ __launch_bounds__(256) void k_cvt_bf16x8(const float* __restrict__ x,
                                                    short* __restrict__ o) {
  int idx = blockIdx.x * 256 + threadIdx.x;
  const float4* p = (const float4*)x;
  float4 a = p[idx * 2];
  float4 b = p[idx * 2 + 1];
  short8 v;
  v[0] = (short)f2bf(a.x); v[1] = (short)f2bf(a.y);
  v[2] = (short)f2bf(a.z); v[3] = (short)f2bf(a.w);
  v[4] = (short)f2bf(b.x); v[5] = (short)f2bf(b.y);
  v[6] = (short)f2bf(b.z); v[7] = (short)f2bf(b.w);
  int row = idx >> 6;
  int dst = row * 512 + ((idx >> 3) & 7) * 64 + (((idx & 7) ^ (row & 7)) << 3);
  *(short8*)&o[dst] = v;
}

// LDS-tiled transpose + swizzle: wt[n][ksw] = bf16(w[k][n]), w is [512][C];
// ksw applies the same per-row (n) chunk XOR swizzle for GEMM staging.
__global__ __launch_bounds__(256) void k_cvt_transpose(const float* __restrict__ w,
                                                       short* __restrict__ wt,
                                                       int C) {
  __shared__ short T[32][33];
  const int tx = threadIdx.x & 31, ty = threadIdx.x >> 5;  // 32 x 8
  const int n0 = blockIdx.x * 32, k0 = blockIdx.y * 32;
#pragma unroll
  for (int i = 0; i < 4; i++) {
    int k = k0 + ty + 8 * i;
    T[ty + 8 * i][tx] = (short)f2bf(w[k * C + n0 + tx]);
  }
  __syncthreads();
#pragma unroll
  for (int i = 0; i < 4; i++) {
    int n = n0 + ty + 8 * i;
    int k = k0 + tx;
    int ksw = (k & ~63) | ((((k >> 3) & 7) ^ (n & 7)) << 3) | (k & 7);
    wt[n * 512 + ksw] = T[tx][ty + 8 * i];
  }
}

// ---------------- GEMM (128x64 tile, BK=64, pipelined, swizzled LDS) --------
// 3 blocks/CU (48KB LDS dbuf). Inputs pre-swizzled in global (chunk ^= row&7
// per 64-col group); linear global_load_lds staging; XOR on LDS read. Single
// barrier per K-step; STAGE(next) issued before compute, drained by the end
// barrier. 4 waves as 2(M)x2(N), each 64x32 (acc[4][2]).
// MODE 0: qkv epilogue (Q pre-scaled, K/VT attn-swizzled). MODE 1: fp32+bias.
template <int MODE>
__global__ __launch_bounds__(256) void k_gemm(const short* __restrict__ A,
                                              const short* __restrict__ Bt,
                                              const float* __restrict__ bias,
                                              short* __restrict__ Qo,
                                              short* __restrict__ Ko,
                                              short* __restrict__ VTo,
                                              float* __restrict__ Fo) {
  __shared__ short As[2][8192];  // [128][64] swizzled
  __shared__ short Bs[2][4096];  // [64][64] swizzled
  const int tid = threadIdx.x;
  const int w = tid >> 6, l = tid & 63, g = l >> 4, c = l & 15;
  const int bm = blockIdx.x * 128, bn = blockIdx.y * 64;
  const int wm = (w >> 1) * 64, wn = (w & 1) * 32;
  f32x4 acc[4][2] = {};
  const short* Ap = A + (bm + (l >> 3)) * 512 + (l & 7) * 8;
  const short* Bp = Bt + (bn + (l >> 3)) * 512 + (l & 7) * 8;
  const int sa0 = w * 4;  // A: 4 segments of 8 rows per wave
  const int sb0 = w * 2;  // B: 2 segments of 8 rows per wave

#define GSTAGE(buf, k0)                                                       \
  {                                                                           \
    GLOAD_LDS16(Ap + (sa0 + 0) * 4096 + (k0), &As[buf][(sa0 + 0) * 512]);     \
    GLOAD_LDS16(Ap + (sa0 + 1) * 4096 + (k0), &As[buf][(sa0 + 1) * 512]);     \
    GLOAD_LDS16(Ap + (sa0 + 2) * 4096 + (k0), &As[buf][(sa0 + 2) * 512]);     \
    GLOAD_LDS16(Ap + (sa0 + 3) * 4096 + (k0), &As[buf][(sa0 + 3) * 512]);     \
    GLOAD_LDS16(Bp + (sb0 + 0) * 4096 + (k0), &Bs[buf][(sb0 + 0) * 512]);     \
    GLOAD_LDS16(Bp + (sb0 + 1) * 4096 + (k0), &Bs[buf][(sb0 + 1) * 512]);     \
  }

  GSTAGE(0, 0);
  __syncthreads();

  const int cs = c & 7;
  int cur = 0;
  for (int k0 = 0; k0 < 512; k0 += 64) {
    if (k0 + 64 < 512) GSTAGE(cur ^ 1, k0 + 64);

    short8 a0[4], a1[4], b0[2], b1[2];
#pragma unroll
    for (int mt = 0; mt < 4; mt++) {
      const short* r = &As[cur][(wm + mt * 16 + c) * 64];
      a0[mt] = *(const short8*)&r[(g ^ cs) << 3];
      a1[mt] = *(const short8*)&r[((g + 4) ^ cs) << 3];
    }
#pragma unroll
    for (int nt = 0; nt < 2; nt++) {
      const short* r = &Bs[cur][(wn + nt * 16 + c) * 64];
      b0[nt] = *(const short8*)&r[(g ^ cs) << 3];
      b1[nt] = *(const short8*)&r[((g + 4) ^ cs) << 3];
    }
#pragma unroll
    for (int mt = 0; mt < 4; mt++)
#pragma unroll
      for (int nt = 0; nt < 2; nt++) {
        acc[mt][nt] = mfma16(a0[mt], b0[nt], acc[mt][nt]);
        acc[mt][nt] = mfma16(a1[mt], b1[nt], acc[mt][nt]);
      }

    __syncthreads();   // drains GSTAGE (vmcnt 0) + read/write buffer sync
    cur ^= 1;
  }
#undef GSTAGE

  if (MODE == 0) {
    const float QS = 0.125f * 1.4426950408889634f;
#pragma unroll
    for (int nt = 0; nt < 2; nt++) {
      int n = bn + wn + nt * 16 + c;
      float bv = bias[n];
      int h = n / 192;
      int t = n - h * 192;
      int type = t >> 6;
      int hd = t & 63;
      float sc = (type == 0) ? QS : 1.0f;
#pragma unroll
      for (int mt = 0; mt < 4; mt++) {
        int m0 = bm + wm + mt * 16 + 4 * g;
        int b = m0 >> 11, ss = m0 & 2047;
        int bh = b * 8 + h;
        if (type == 2) {
          int sw = (ss & ~63) | (((((ss >> 3) & 7) ^ (hd & 7)) << 3)) | (ss & 7);
          short4v pk;
#pragma unroll
          for (int r = 0; r < 4; r++) pk[r] = (short)f2bf(acc[mt][nt][r] + bv);
          *(short4v*)&VTo[(bh * 64 + hd) * 2048 + sw] = pk;
        } else if (type == 1) {
#pragma unroll
          for (int r = 0; r < 4; r++) {
            int s = ss + r;
            int hds = ((((hd >> 3) ^ (s & 7)) << 3)) | (hd & 7);
            Ko[(bh * 2048 + s) * 64 + hds] = (short)f2bf(acc[mt][nt][r] + bv);
          }
        } else {
#pragma unroll
          for (int r = 0; r < 4; r++)
            Qo[(bh * 2048 + ss + r) * 64 + hd] = (short)f2bf((acc[mt][nt][r] + bv) * sc);
        }
      }
    }
  } else {
#pragma unroll
    for (int nt = 0; nt < 2; nt++) {
      int n = bn + wn + nt * 16 + c;
      float bv = bias[n];
#pragma unroll
      for (int mt = 0; mt < 4; mt++) {
        int m0 = bm + wm + mt * 16 + 4 * g;
#pragma unroll
        for (int r = 0; r < 4; r++) Fo[(m0 + r) * 512 + n] = acc[mt][nt][r] + bv;
      }
    }
  }
}

// ---------------- flash attention (double-buffered, exp2-builtin) ----------------
// Unchanged from round 11 (ctx store carries the GEMM-staging row swizzle).
__global__ __launch_bounds__(256, 4) void k_attn(const short* __restrict__ Q,
                                                 const short* __restrict__ K,
                                                 const short* __restrict__ VT,
                                                 short* __restrict__ ctx) {
  __shared__ short Ks[2][4096];   // [64 kv][64 hd] swizzled
  __shared__ short Vs[2][4096];   // [64 hd][64 kv] swizzled
  __shared__ short P[4][1024];    // per-wave [16 q][64 kv] swizzled
  const int tid = threadIdx.x;
  const int w = tid >> 6, l = tid & 63, g = l >> 4, c = l & 15;

  const int x = blockIdx.x;
  const int bh = x & 31;
  const int jc = 31 - (x >> 5);    // 0..31, heaviest first
  const int qbase = jc * 64 + w * 16;
  const int ntiles = jc + 1;

  const short* Qb = Q + bh * S_ * HD_;
  const short* Kb = K + bh * S_ * HD_;
  const short* Vb = VT + bh * HD_ * S_;

  const int i0 = tid, i1 = tid + 256;
  const int kr0 = i0 >> 3, kc0 = (i0 & 7) * 8;
  const int kr1 = i1 >> 3, kc1 = (i1 & 7) * 8;
  short* KL0 = &Ks[0][w * 512];
  short* KL1 = &Ks[0][2048 + w * 512];
  short* VL0 = &Vs[0][w * 512];
  short* VL1 = &Vs[0][2048 + w * 512];

#define STAGE(buf, kv0)                                                     \
  {                                                                         \
    GLOAD_LDS16(Kb + ((kv0) + kr0) * 64 + kc0, KL0 + (buf)*4096);           \
    GLOAD_LDS16(Kb + ((kv0) + kr1) * 64 + kc1, KL1 + (buf)*4096);           \
    GLOAD_LDS16(Vb + kr0 * 2048 + (kv0) + kc0, VL0 + (buf)*4096);           \
    GLOAD_LDS16(Vb + kr1 * 2048 + (kv0) + kc1, VL1 + (buf)*4096);           \
  }

  short* Pw = &P[w][0];
  const int bb = bh >> 3, hh = bh & 7;
  const f32x4 CINIT = {-16.f, -16.f, -16.f, -16.f};

  short8 qf0 = *(const short8*)&Qb[(qbase + c) * 64 + 8 * g];
  short8 qf1 = *(const short8*)&Qb[(qbase + c) * 64 + 8 * g + 32];

  f32x4 o[4];
  float psum[4];
#pragma unroll
  for (int nt = 0; nt < 4; nt++) o[nt] = f32x4{0.f, 0.f, 0.f, 0.f};
#pragma unroll
  for (int r = 0; r < 4; r++) psum[r] = 0.f;

  STAGE(0, 0);
  __syncthreads();

  int cur = 0;
  for (int it = 0; it < ntiles; ++it) {
    const int kv0 = it * 64;
    if (it + 1 < ntiles) STAGE(cur ^ 1, kv0 + 64);

    const short* Kt = &Ks[cur][0];
    const short* Vt = &Vs[cur][0];

    // QK^T from LDS (swizzle-read); C-init = -16 folds the softmax offset
    f32x4 sa[4];
#pragma unroll
    for (int nt = 0; nt < 4; nt++) {
      short8 kf0 = *(const short8*)&Kt[((nt * 16 + c) << 6) + ((g ^ (c & 7)) << 3)];
      short8 kf1 = *(const short8*)&Kt[((nt * 16 + c) << 6) + (((g + 4) ^ (c & 7)) << 3)];
      sa[nt] = mfma16(qf0, kf0, CINIT);
      sa[nt] = mfma16(qf1, kf1, sa[nt]);
    }

    // causal mask (only the diagonal tile for this wave's rows)
    if (kv0 + 64 > qbase) {
#pragma unroll
      for (int nt = 0; nt < 4; nt++) {
        int kv = kv0 + nt * 16 + c;
#pragma unroll
        for (int r = 0; r < 4; r++) {
          int qrow = qbase + 4 * g + r;
          if (kv > qrow) sa[nt][r] = -1e30f;
        }
      }
    }

    // p = exp2(s) via raw v_exp_f32; partial row sums; pack to swizzled P
#pragma unroll
    for (int nt = 0; nt < 4; nt++)
#pragma unroll
      for (int r = 0; r < 4; r++) {
        float pv = __builtin_amdgcn_exp2f(sa[nt][r]);
        psum[r] += pv;
        int row = 4 * g + r;
        int col = nt * 16 + c;
        int off = (row << 6) + ((((col >> 3) ^ (row & 7)) << 3)) + (col & 7);
        Pw[off] = (short)f2bf(pv);
      }

    // PV from LDS P and V (swizzle-read)
#pragma unroll
    for (int kvb = 0; kvb < 2; kvb++) {
      short8 pa = *(const short8*)&Pw[(c << 6) + (((kvb * 4 + g) ^ (c & 7)) << 3)];
#pragma unroll
      for (int nt = 0; nt < 4; nt++) {
        short8 vb = *(const short8*)&Vt[((nt * 16 + c) << 6) +
                                        (((kvb * 4 + g) ^ (c & 7)) << 3)];
        o[nt] = mfma16(pa, vb, o[nt]);
      }
    }

    __syncthreads();   // drains this iter's STAGE (vmcnt 0) + buffer swap sync
    cur ^= 1;
  }

  // row-sum reduce over the 16 c-lanes in each g-group
#pragma unroll
  for (int off = 1; off < 16; off <<= 1)
#pragma unroll
    for (int r = 0; r < 4; r++) psum[r] += __shfl_xor(psum[r], off, 64);

  float inv[4];
#pragma unroll
  for (int r = 0; r < 4; r++) inv[r] = 1.0f / psum[r];
#pragma unroll
  for (int nt = 0; nt < 4; nt++)
#pragma unroll
    for (int r = 0; r < 4; r++) {
      int srow = qbase + 4 * g + r;
      int colsw = hh * 64 + (((nt * 2 + (c >> 3)) ^ (srow & 7)) << 3) + (c & 7);
      ctx[(bb * S_ + srow) * 512 + colsw] = (short)f2bf(o[nt][r] * inv[r]);
    }
#undef STAGE
}

// ---------------- launcher ----------------

extern "C" void kernel_launch(void* const* d_in, const int* in_sizes, int n_in,
                              void* d_out, int out_size, void* d_ws, size_t ws_size,
                              hipStream_t stream) {
  const float* x = (const float*)d_in[0];
  const float* Wqkv = (const float*)d_in[2];
  const float* bqkv = (const float*)d_in[3];
  const float* Wo = (const float*)d_in[4];
  const float* bo = (const float*)d_in[5];
  float* out = (float*)d_out;

  char* ws = (char*)d_ws;
  short* xb    = (short*)(ws + 0);
  short* wqkvt = (short*)(ws + 8388608);
  short* wot   = (short*)(ws + 9961472);
  short* Qw    = (short*)(ws + 10485760);
  short* Kw    = (short*)(ws + 18874368);
  short* VTw   = (short*)(ws + 27262976);
  short* ctx   = (short*)(ws + 35651584);

  k_cvt_bf16x8<<<2048, 256, 0, stream>>>(x, xb);
  {
    dim3 gt(48, 16);
    k_cvt_transpose<<<gt, 256, 0, stream>>>(Wqkv, wqkvt, 1536);
    dim3 gt2(16, 16);
    k_cvt_transpose<<<gt2, 256, 0, stream>>>(Wo, wot, 512);
  }

  dim3 g1(64, 24);
  k_gemm<0><<<g1, 256, 0, stream>>>(xb, wqkvt, bqkv, Qw, Kw, VTw, nullptr);

  k_attn<<<1024, 256, 0, stream>>>(Qw, Kw, VTw, ctx);

  dim3 g3(64, 8);
  k_gemm<1><<<g3, 256, 0, stream>>>(ctx, wot, bo, nullptr, nullptr, nullptr, out);
}